// Round 1
// baseline (61.073 us; speedup 1.0000x reference)
//
#include <hip/hip_runtime.h>
#include <math.h>

// One thread per edge. Rows 4e+1..4e+3 of lig/rec are used; we load the full
// 48B (12 floats) per edge per array as 3 aligned float4s for coalescing.
// Weights (~1465 floats) are uniform + constant-indexed after unroll ->
// compiler emits s_load into SGPRs (scalar cache), VALU does v_fma with
// SGPR operand.

__global__ __launch_bounds__(256) void fds_kernel(
    const float* __restrict__ lig, const float* __restrict__ rec,
    const float* __restrict__ W1_sso, const float* __restrict__ W1_svv,
    const float* __restrict__ W1_vsv, const float* __restrict__ W1_vvo,
    const float* __restrict__ W1_vvv, const float* __restrict__ W2_sso,
    const float* __restrict__ W2_svv, const float* __restrict__ W2_vsv,
    const float* __restrict__ W2_vvo, const float* __restrict__ W2_vvv,
    float* __restrict__ out, int E)
{
    const float INV_SQRT2   = 0.70710678118654752f;
    const float INV_SQRT3   = 0.57735026918962576f;
    const float INV_SQRT21  = 0.21821789023599239f;
    const float INV_SQRT10  = 0.31622776601683794f;
    const float INV_SQRT105 = 0.09759000729485332f;
    const float INV_SQRT50  = 0.14142135623730950f;
    const float C5 = -0.32f;                 // -0.5 / 1.25^2
    const float OFF4 = 5.0f / 3.0f;
    const float C4 = -0.5f / (OFF4 * OFF4);

    int e = blockIdx.x * blockDim.x + threadIdx.x;
    if (e >= E) return;

    const float4* lp = (const float4*)lig + 3 * (size_t)e;
    const float4* rp = (const float4*)rec + 3 * (size_t)e;
    float4 l0 = lp[0], l1 = lp[1], l2 = lp[2];
    float4 r0 = rp[0], r1 = rp[1], r2 = rp[2];

    // row 4e+1 = floats 3..5, row 4e+2 = floats 6..8, row 4e+3 = floats 9..11
    float e1x = l0.w - r0.w, e1y = l1.x - r1.x, e1z = l1.y - r1.y;
    float e2x = l1.z - r1.z, e2y = l1.w - r1.w, e2z = l2.x - r2.x;
    float e3x = l2.y - r2.y, e3y = l2.z - r2.z, e3z = l2.w - r2.w;

    float q1 = fmaf(e1x, e1x, fmaf(e1y, e1y, e1z * e1z)) + 1e-12f;
    float q2 = fmaf(e2x, e2x, fmaf(e2y, e2y, e2z * e2z)) + 1e-12f;
    float q3 = fmaf(e3x, e3x, fmaf(e3y, e3y, e3z * e3z)) + 1e-12f;
    float ri1 = rsqrtf(q1), ri2 = rsqrtf(q2), ri3 = rsqrtf(q3);
    float d1 = q1 * ri1, d2 = q2 * ri2, d3 = q3 * ri3;
    float v1x = e1x * ri1, v1y = e1y * ri1, v1z = e1z * ri1;
    float v2x = e2x * ri2, v2y = e2y * ri2, v2z = e2z * ri2;
    float v3x = e3x * ri3, v3y = e3y * ri3, v3z = e3z * ri3;

    float s1[5], s3[5], s2[4];
#pragma unroll
    for (int i = 0; i < 5; i++) { float t = d1 - 1.25f * i; s1[i] = __expf(C5 * t * t); }
#pragma unroll
    for (int i = 0; i < 5; i++) { float t = d3 - 1.25f * i; s3[i] = __expf(C5 * t * t); }
#pragma unroll
    for (int j = 0; j < 4; j++) { float t = d2 - OFF4 * j; s2[j] = __expf(C4 * t * t); }

    float dot12 = fmaf(v1x, v2x, fmaf(v1y, v2y, v1z * v2z)) * INV_SQRT3;
    float cr12x = (v1y * v2z - v1z * v2y) * INV_SQRT2;
    float cr12y = (v1z * v2x - v1x * v2z) * INV_SQRT2;
    float cr12z = (v1x * v2y - v1y * v2x) * INV_SQRT2;

    // layer 1 scalar path: out_s[k] = (sum_ij s1 s2 W1_sso + dot12*W1_vvo) / sqrt21
    float p12[20];
#pragma unroll
    for (int i = 0; i < 5; i++)
#pragma unroll
        for (int j = 0; j < 4; j++) p12[i * 4 + j] = s1[i] * s2[j];

    float os[20];
#pragma unroll
    for (int k = 0; k < 20; k++) os[k] = dot12 * W1_vvo[k];
#pragma unroll
    for (int ij = 0; ij < 20; ij++) {
        float p = p12[ij];
#pragma unroll
        for (int k = 0; k < 20; k++) os[k] = fmaf(p, W1_sso[ij * 20 + k], os[k]);
    }
#pragma unroll
    for (int k = 0; k < 20; k++) os[k] *= INV_SQRT21;

    // layer 1 vector path
    float A[5], B[5];
#pragma unroll
    for (int k = 0; k < 5; k++) {
        float a = 0.f, b = 0.f;
#pragma unroll
        for (int i = 0; i < 5; i++) a = fmaf(s1[i], W1_svv[i * 5 + k], a);
#pragma unroll
        for (int j = 0; j < 4; j++) b = fmaf(s2[j], W1_vsv[j * 5 + k], b);
        A[k] = a; B[k] = b;
    }
    float ov[5][3];
#pragma unroll
    for (int k = 0; k < 5; k++) {
        float w = W1_vvv[k];
        ov[k][0] = (A[k] * v2x + B[k] * v1x + cr12x * w) * INV_SQRT10;
        ov[k][1] = (A[k] * v2y + B[k] * v1y + cr12y * w) * INV_SQRT10;
        ov[k][2] = (A[k] * v2z + B[k] * v1z + cr12z * w) * INV_SQRT10;
    }

    // layer 2
    float dot2[5];
#pragma unroll
    for (int k = 0; k < 5; k++)
        dot2[k] = fmaf(ov[k][0], v3x, fmaf(ov[k][1], v3y, ov[k][2] * v3z)) * INV_SQRT3;

    float accs[9];
#pragma unroll
    for (int o = 0; o < 9; o++) accs[o] = 0.f;
#pragma unroll
    for (int k = 0; k < 5; k++)
#pragma unroll
        for (int o = 0; o < 9; o++) accs[o] = fmaf(dot2[k], W2_vvo[k * 9 + o], accs[o]);
#pragma unroll
    for (int k2 = 0; k2 < 20; k2++) {
        float t = os[k2];
#pragma unroll
        for (int j = 0; j < 5; j++) {
            float f = t * s3[j];
#pragma unroll
            for (int o = 0; o < 9; o++)
                accs[o] = fmaf(f, W2_sso[k2 * 45 + j * 9 + o], accs[o]);
        }
    }

    float S = 0.f;
#pragma unroll
    for (int i = 0; i < 20; i++) S = fmaf(os[i], W2_svv[i], S);
    float Ck[5];
#pragma unroll
    for (int k = 0; k < 5; k++) {
        float c = 0.f;
#pragma unroll
        for (int j = 0; j < 5; j++) c = fmaf(s3[j], W2_vsv[k * 5 + j], c);
        Ck[k] = c;
    }
    float av0 = S * v3x, av1 = S * v3y, av2 = S * v3z;
#pragma unroll
    for (int k = 0; k < 5; k++) {
        float w = W2_vvv[k];
        float cx = (ov[k][1] * v3z - ov[k][2] * v3y) * INV_SQRT2;
        float cy = (ov[k][2] * v3x - ov[k][0] * v3z) * INV_SQRT2;
        float cz = (ov[k][0] * v3y - ov[k][1] * v3x) * INV_SQRT2;
        av0 += ov[k][0] * Ck[k] + cx * w;
        av1 += ov[k][1] * Ck[k] + cy * w;
        av2 += ov[k][2] * Ck[k] + cz * w;
    }

    size_t E3 = (size_t)E * 3;
    size_t b = (size_t)e * 3;
    out[b + 0]          = accs[0] * INV_SQRT105;   // s_rot
    out[b + 1]          = accs[1] * INV_SQRT105;
    out[b + 2]          = accs[2] * INV_SQRT105;
    out[E3 + b + 0]     = accs[3] * INV_SQRT105;   // s_tr
    out[E3 + b + 1]     = accs[4] * INV_SQRT105;
    out[E3 + b + 2]     = accs[5] * INV_SQRT105;
    out[2 * E3 + b + 0] = accs[6] * INV_SQRT105;   // t_rot
    out[2 * E3 + b + 1] = accs[7] * INV_SQRT105;
    out[2 * E3 + b + 2] = accs[8] * INV_SQRT105;
    out[3 * E3 + b + 0] = av0 * INV_SQRT50;        // t_tr
    out[3 * E3 + b + 1] = av1 * INV_SQRT50;
    out[3 * E3 + b + 2] = av2 * INV_SQRT50;
}

extern "C" void kernel_launch(void* const* d_in, const int* in_sizes, int n_in,
                              void* d_out, int out_size, void* d_ws, size_t ws_size,
                              hipStream_t stream) {
    const float* lig    = (const float*)d_in[0];
    const float* rec    = (const float*)d_in[1];
    const float* W1_sso = (const float*)d_in[2];
    const float* W1_svv = (const float*)d_in[3];
    const float* W1_vsv = (const float*)d_in[4];
    const float* W1_vvo = (const float*)d_in[5];
    const float* W1_vvv = (const float*)d_in[6];
    const float* W2_sso = (const float*)d_in[7];
    const float* W2_svv = (const float*)d_in[8];
    const float* W2_vsv = (const float*)d_in[9];
    const float* W2_vvo = (const float*)d_in[10];
    const float* W2_vvv = (const float*)d_in[11];

    int E = in_sizes[0] / 12;  // N*3 / 12 = N/4
    int blocks = (E + 255) / 256;
    fds_kernel<<<blocks, 256, 0, stream>>>(lig, rec, W1_sso, W1_svv, W1_vsv,
                                           W1_vvo, W1_vvv, W2_sso, W2_svv,
                                           W2_vsv, W2_vvo, W2_vvv,
                                           (float*)d_out, E);
}